// Round 14
// baseline (127.359 us; speedup 1.0000x reference)
//
#include <hip/hip_runtime.h>

// Problem constants: B=8, C=128, L=2048, H=4, D=32
#define Bsz 8
#define Cdim 128
#define Lseq 2048
#define NH 4
#define HD 32
#define BH 32
// 1/sqrt(D) * log2(e): scores feed exp2 directly
#define QSCALE (0.17677669529663687f * 1.4426950408889634f)

typedef __bf16 bf16x8 __attribute__((ext_vector_type(8)));
typedef float f32x4 __attribute__((ext_vector_type(4)));
typedef unsigned u32x4 __attribute__((ext_vector_type(4)));

__device__ __forceinline__ unsigned short f2bf(float f) {   // RNE
    unsigned u = __builtin_bit_cast(unsigned, f);
    u += 0x7FFFu + ((u >> 16) & 1u);
    return (unsigned short)(u >> 16);
}

__device__ __forceinline__ unsigned pack_bf16(float a, float b) {  // RNE pair
    return (unsigned)f2bf(a) | ((unsigned)f2bf(b) << 16);
}

// RTZ pack of two f32 -> packed bf16x2, single v_perm_b32.
__device__ __forceinline__ unsigned pack_bf16_rtz(float a, float b) {
    return __builtin_amdgcn_perm(__builtin_bit_cast(unsigned, b),
                                 __builtin_bit_cast(unsigned, a), 0x07060302u);
}

__device__ __forceinline__ float bf_lo(unsigned u) {
    return __builtin_bit_cast(float, u << 16);
}
__device__ __forceinline__ float bf_hi(unsigned u) {
    return __builtin_bit_cast(float, u & 0xFFFF0000u);
}

// Polynomial 2^s on the FULL-RATE VALU pipe (not the quarter-rate trans
// unit). floor + fract + 4 FMA + cvt + v_ldexp_f32. deg-4 on [0,1):
// rel err ~1e-4, far below bf16 (4e-3). Numerator and denominator use the
// same P values, so any poly bias cancels in the softmax ratio.
__device__ __forceinline__ float poly_exp2(float s) {
    float n = __builtin_floorf(s);
    float f = s - n;
    float p = __builtin_fmaf(f, 0.0089893397f, 0.0558969596f);
    p = __builtin_fmaf(f, p, 0.2401536316f);
    p = __builtin_fmaf(f, p, 0.6931530732f);
    p = __builtin_fmaf(f, p, 0.9999999702f);
#if __has_builtin(__builtin_amdgcn_ldexpf)
    return __builtin_amdgcn_ldexpf(p, (int)n);
#else
    return __builtin_ldexpf(p, (int)n);
#endif
}

#define MFMA16(A, B, C) __builtin_amdgcn_mfma_f32_16x16x32_bf16((A), (B), (C), 0, 0, 0)

// ---------------------------------------------------------------------------
// Kernel 1: QKV projection, fused staging (unchanged — verified R9-R13).
// Q,K -> [bh][l][32]; V -> kappa-permuted tile [bh][kc64][d32][pos64].
// ---------------------------------------------------------------------------
__global__ __launch_bounds__(256) void qkv_kernel(const float* __restrict__ x,
        const float* __restrict__ w, const float* __restrict__ bias,
        unsigned short* __restrict__ qh, unsigned short* __restrict__ kh,
        unsigned short* __restrict__ vh) {
    __shared__ __attribute__((aligned(16))) unsigned short T[64][132];
    int bid = blockIdx.x;
    int og = bid % 6;                 // 6 o-groups of 64
    int lt = (bid / 6) & 31;          // 32 l-tiles of 64
    int b  = bid / 192;
    int l0 = lt * 64;
    int t = threadIdx.x;
    int lane = t & 63, wv = t >> 6;
    int m16 = lane & 15, quad = lane >> 4;
    int o0 = og * 64 + wv * 16;

    bf16x8 af[4];
    #pragma unroll
    for (int ks = 0; ks < 4; ks++) {
        const float* p = w + (size_t)(o0 + m16) * Cdim + ks * 32 + quad * 8;
        float4 f0 = *(const float4*)p;
        float4 f1 = *(const float4*)(p + 4);
        u32x4 u = {pack_bf16(f0.x, f0.y), pack_bf16(f0.z, f0.w),
                   pack_bf16(f1.x, f1.y), pack_bf16(f1.z, f1.w)};
        af[ks] = __builtin_bit_cast(bf16x8, u);
    }
    float bs[4];
    #pragma unroll
    for (int r = 0; r < 4; r++) bs[r] = bias[o0 + quad * 4 + r];

    {
        int ll = t & 63, cg = t >> 6;
        const float* xb = x + (size_t)b * Cdim * Lseq + l0 + ll;
        #pragma unroll
        for (int i = 0; i < 16; i++) {
            int c = cg * 32 + 2 * i;
            float f0 = xb[(size_t)c * Lseq];
            float f1 = xb[(size_t)(c + 1) * Lseq];
            *(unsigned*)&T[ll][c] = pack_bf16(f0, f1);
        }
    }
    __syncthreads();

    int oq = o0 + quad * 4;
    #pragma unroll
    for (int ns = 0; ns < 4; ns++) {
        bf16x8 bx[4];
        #pragma unroll
        for (int ks = 0; ks < 4; ks++)
            bx[ks] = *(const bf16x8*)(&T[ns * 16 + m16][ks * 32 + quad * 8]);
        f32x4 acc = {0.f, 0.f, 0.f, 0.f};
        #pragma unroll
        for (int ks = 0; ks < 4; ks++) acc = MFMA16(af[ks], bx[ks], acc);
        int l = l0 + ns * 16 + m16;
        if (og < 2) {            // Q (scaled)
            int h = oq >> 5, d0 = oq & 31;
            uint2 u;
            u.x = pack_bf16((acc[0] + bs[0]) * QSCALE, (acc[1] + bs[1]) * QSCALE);
            u.y = pack_bf16((acc[2] + bs[2]) * QSCALE, (acc[3] + bs[3]) * QSCALE);
            *(uint2*)(qh + ((size_t)(b * NH + h) * Lseq + l) * HD + d0) = u;
        } else if (og < 4) {     // K
            int o = oq - Cdim, h = o >> 5, d0 = o & 31;
            uint2 u;
            u.x = pack_bf16(acc[0] + bs[0], acc[1] + bs[1]);
            u.y = pack_bf16(acc[2] + bs[2], acc[3] + bs[3]);
            *(uint2*)(kh + ((size_t)(b * NH + h) * Lseq + l) * HD + d0) = u;
        } else {                 // V kappa-permuted tiled store
            int kc = l >> 6, kk = l & 63;
            int half = kk >> 5, k32 = kk & 31;
            int q_, j_;
            if (k32 < 16) { q_ = k32 >> 2; j_ = k32 & 3; }
            else          { q_ = (k32 - 16) >> 2; j_ = 4 + ((k32 - 16) & 3); }
            int pos = half * 32 + q_ * 8 + j_;
            #pragma unroll
            for (int r = 0; r < 4; r++) {
                int o = oq + r - 2 * Cdim, h = o >> 5, d = o & 31;
                vh[(((size_t)(b * NH + h) * 32 + kc) * HD + d) * 64 + pos] =
                    f2bf(acc[r] + bs[r]);
            }
        }
    }
}

// ---------------------------------------------------------------------------
// Kernel 2: MFMA flash attention — R12 structure (best: 118.3 us), with
// exp moved OFF the quarter-rate trans unit onto the full-rate VALU pipe
// (poly_exp2). Tests the hypothesis that the serial 256-cyc trans bursts
// per q-subtile are the unexplained stall (trans util ~36% == VALUBusy).
// Grid 2048 = (xcd bh, qt, key-half); wave = 64 q x 256 keys; A/B
// double-buffered loads; kappa-packed P; kappa-stored V; ones-MFMA rowsums.
// ---------------------------------------------------------------------------
__global__ __launch_bounds__(256) void attn_kernel(
        const unsigned short* __restrict__ qh, const unsigned short* __restrict__ kh,
        const unsigned short* __restrict__ vh, unsigned short* __restrict__ po,
        float* __restrict__ pl) {
    // red_o: [4][64] rows x 18 uints = 18432 B; red_l: [4][64] float @18432
    __shared__ __attribute__((aligned(16))) char smem[19456];

    int bid = blockIdx.x;
    int xcd  = bid & 7;                 // same bh -> same XCD (K/V L2 residency)
    int rest = bid >> 3;
    int qt = rest & 31;
    int hb = rest >> 5;                 // 0..7
    int bh = xcd + 8 * (hb & 3);
    int half = hb >> 2;

    int lane = threadIdx.x & 63;
    int wv   = threadIdx.x >> 6;
    int m16  = lane & 15;
    int quad = lane >> 4;
    int l0 = qt * 64;

    bf16x8 qf[4];
    #pragma unroll
    for (int qs = 0; qs < 4; qs++)
        qf[qs] = *(const bf16x8*)(qh + ((size_t)bh * Lseq + l0 + qs * 16 + m16) * HD + quad * 8);

    bf16x8 ones;
    #pragma unroll
    for (int i = 0; i < 8; i++) ones[i] = (__bf16)1.0f;

    f32x4 oacc[4][2];
    f32x4 lacc[4];
    #pragma unroll
    for (int qs = 0; qs < 4; qs++) {
        oacc[qs][0] = f32x4{0.f, 0.f, 0.f, 0.f};
        oacc[qs][1] = f32x4{0.f, 0.f, 0.f, 0.f};
        lacc[qs]    = f32x4{0.f, 0.f, 0.f, 0.f};
    }
    f32x4 zero = {0.f, 0.f, 0.f, 0.f};

    const unsigned short* kb = kh + (size_t)bh * Lseq * HD + m16 * HD + quad * 8;
    const unsigned short* vb = vh + (size_t)bh * 32 * HD * 64;
    int kbase = half * 1024 + wv * 256;

    auto load_kv = [&](int chunk, bf16x8* kf, bf16x8* vf) {
        int k0 = kbase + chunk * 64;
        #pragma unroll
        for (int t = 0; t < 4; t++)
            kf[t] = *(const bf16x8*)(kb + (size_t)(k0 + 16 * t) * HD);
        const unsigned short* vch = vb + (size_t)(k0 >> 6) * (HD * 64);
        vf[0] = *(const bf16x8*)(vch + m16 * 64 + quad * 8);
        vf[1] = *(const bf16x8*)(vch + (16 + m16) * 64 + quad * 8);
        vf[2] = *(const bf16x8*)(vch + m16 * 64 + 32 + quad * 8);
        vf[3] = *(const bf16x8*)(vch + (16 + m16) * 64 + 32 + quad * 8);
    };

    auto compute = [&](const bf16x8* kf, const bf16x8* vf) {
        #pragma unroll
        for (int qs = 0; qs < 4; qs++) {
            f32x4 s0 = MFMA16(kf[0], qf[qs], zero);
            f32x4 s1 = MFMA16(kf[1], qf[qs], zero);
            f32x4 s2 = MFMA16(kf[2], qf[qs], zero);
            f32x4 s3 = MFMA16(kf[3], qf[qs], zero);
            float p00 = poly_exp2(s0[0]), p01 = poly_exp2(s0[1]),
                  p02 = poly_exp2(s0[2]), p03 = poly_exp2(s0[3]);
            float p10 = poly_exp2(s1[0]), p11 = poly_exp2(s1[1]),
                  p12 = poly_exp2(s1[2]), p13 = poly_exp2(s1[3]);
            float p20 = poly_exp2(s2[0]), p21 = poly_exp2(s2[1]),
                  p22 = poly_exp2(s2[2]), p23 = poly_exp2(s2[3]);
            float p30 = poly_exp2(s3[0]), p31 = poly_exp2(s3[1]),
                  p32 = poly_exp2(s3[2]), p33 = poly_exp2(s3[3]);
            // packed regs ARE the P B-frag in kappa key-order
            u32x4 lo = {pack_bf16_rtz(p00, p01), pack_bf16_rtz(p02, p03),
                        pack_bf16_rtz(p10, p11), pack_bf16_rtz(p12, p13)};
            u32x4 hi = {pack_bf16_rtz(p20, p21), pack_bf16_rtz(p22, p23),
                        pack_bf16_rtz(p30, p31), pack_bf16_rtz(p32, p33)};
            bf16x8 pfL = __builtin_bit_cast(bf16x8, lo);
            bf16x8 pfH = __builtin_bit_cast(bf16x8, hi);
            oacc[qs][0] = MFMA16(vf[0], pfL, oacc[qs][0]);
            oacc[qs][1] = MFMA16(vf[1], pfL, oacc[qs][1]);
            lacc[qs]    = MFMA16(ones,  pfL, lacc[qs]);
            oacc[qs][0] = MFMA16(vf[2], pfH, oacc[qs][0]);
            oacc[qs][1] = MFMA16(vf[3], pfH, oacc[qs][1]);
            lacc[qs]    = MFMA16(ones,  pfH, lacc[qs]);
        }
    };

    bf16x8 kA[4], vA[4], kB[4], vB[4];
    load_kv(0, kA, vA);
    load_kv(1, kB, vB);
    compute(kA, vA);
    load_kv(2, kA, vA);
    compute(kB, vB);
    load_kv(3, kB, vB);
    compute(kA, vA);
    compute(kB, vB);

    // cross-wave reduction: packed-bf16 partials, one barrier
    unsigned* red_o = (unsigned*)smem;               // [4*64 rows][18]
    float* red_l = (float*)(smem + 18432);
    #pragma unroll
    for (int qs = 0; qs < 4; qs++) {
        int row = qs * 16 + m16;
        unsigned* rw = red_o + (size_t)(wv * 64 + row) * 18;
        *(uint2*)(rw + 2 * quad) =
            make_uint2(pack_bf16_rtz(oacc[qs][0][0], oacc[qs][0][1]),
                       pack_bf16_rtz(oacc[qs][0][2], oacc[qs][0][3]));
        *(uint2*)(rw + 8 + 2 * quad) =
            make_uint2(pack_bf16_rtz(oacc[qs][1][0], oacc[qs][1][1]),
                       pack_bf16_rtz(oacc[qs][1][2], oacc[qs][1][3]));
        if (quad == 0) red_l[wv * 64 + row] = lacc[qs][0];  // rowsum (replicated)
    }
    __syncthreads();

    // combine 4 waves -> UNNORMALIZED bf16 partials to ws
    int q = threadIdx.x >> 2;
    int s4 = (threadIdx.x & 3) * 4;
    float a8[8] = {0.f, 0.f, 0.f, 0.f, 0.f, 0.f, 0.f, 0.f};
    float lt = 0.f;
    #pragma unroll
    for (int w = 0; w < 4; w++) {
        const unsigned* rr = red_o + (size_t)(w * 64 + q) * 18 + s4;
        uint2 ua = *(const uint2*)(rr);
        uint2 ub = *(const uint2*)(rr + 2);
        a8[0] += bf_lo(ua.x); a8[1] += bf_hi(ua.x);
        a8[2] += bf_lo(ua.y); a8[3] += bf_hi(ua.y);
        a8[4] += bf_lo(ub.x); a8[5] += bf_hi(ub.x);
        a8[6] += bf_lo(ub.y); a8[7] += bf_hi(ub.y);
        lt += red_l[w * 64 + q];
    }
    int d0 = (threadIdx.x & 3) * 8;
    uint4 u;
    u.x = pack_bf16(a8[0], a8[1]);
    u.y = pack_bf16(a8[2], a8[3]);
    u.z = pack_bf16(a8[4], a8[5]);
    u.w = pack_bf16(a8[6], a8[7]);
    *(uint4*)(po + ((size_t)(half * BH + bh) * Lseq + l0 + q) * HD + d0) = u;
    if ((threadIdx.x & 3) == 0)
        pl[(size_t)(half * BH + bh) * Lseq + l0 + q] = lt;
}

// ---------------------------------------------------------------------------
// Kernel 3: combine key-halves + normalize + projection + bias + residual.
// (unchanged from R12) Grid 1024: block = 64 o x 32 n.
// ---------------------------------------------------------------------------
__global__ __launch_bounds__(256) void proj_kernel(const float* __restrict__ wp,
        const unsigned short* __restrict__ po, const float* __restrict__ pl,
        const float* __restrict__ bias, const float* __restrict__ x,
        float* __restrict__ out) {
    __shared__ __attribute__((aligned(16))) unsigned short T[32][132];
    int bid = blockIdx.x;
    int ot = bid & 1;
    int nt = bid >> 1;                // 0..511, 32-n tiles
    int n0 = nt * 32;
    int t = threadIdx.x;

    {
        int nl = t >> 3, g = t & 7;
        int h = g >> 1, d0 = (g & 1) * 16;
        int n = n0 + nl, b = n >> 11, l = n & (Lseq - 1);
        int bh = b * NH + h;
        const unsigned short* p0 = po + ((size_t)bh * Lseq + l) * HD + d0;
        const unsigned short* p1 = po + ((size_t)(BH + bh) * Lseq + l) * HD + d0;
        float inv = 1.0f / (pl[(size_t)bh * Lseq + l] + pl[(size_t)(BH + bh) * Lseq + l]);
        uint4 a0 = *(const uint4*)p0, a1 = *(const uint4*)(p0 + 8);
        uint4 b0 = *(const uint4*)p1, b1 = *(const uint4*)(p1 + 8);
        uint4 u0, u1;
        u0.x = pack_bf16((bf_lo(a0.x) + bf_lo(b0.x)) * inv, (bf_hi(a0.x) + bf_hi(b0.x)) * inv);
        u0.y = pack_bf16((bf_lo(a0.y) + bf_lo(b0.y)) * inv, (bf_hi(a0.y) + bf_hi(b0.y)) * inv);
        u0.z = pack_bf16((bf_lo(a0.z) + bf_lo(b0.z)) * inv, (bf_hi(a0.z) + bf_hi(b0.z)) * inv);
        u0.w = pack_bf16((bf_lo(a0.w) + bf_lo(b0.w)) * inv, (bf_hi(a0.w) + bf_hi(b0.w)) * inv);
        u1.x = pack_bf16((bf_lo(a1.x) + bf_lo(b1.x)) * inv, (bf_hi(a1.x) + bf_hi(b1.x)) * inv);
        u1.y = pack_bf16((bf_lo(a1.y) + bf_lo(b1.y)) * inv, (bf_hi(a1.y) + bf_hi(b1.y)) * inv);
        u1.z = pack_bf16((bf_lo(a1.z) + bf_lo(b1.z)) * inv, (bf_hi(a1.z) + bf_hi(b1.z)) * inv);
        u1.w = pack_bf16((bf_lo(a1.w) + bf_lo(b1.w)) * inv, (bf_hi(a1.w) + bf_hi(b1.w)) * inv);
        int c0 = g * 16;
        *(uint4*)&T[nl][c0]     = u0;
        *(uint4*)&T[nl][c0 + 8] = u1;
    }

    int lane = t & 63;
    int wv = t >> 6;
    int m16 = lane & 15, quad = lane >> 4;
    int o0 = ot * 64 + wv * 16;

    bf16x8 af[4];
    #pragma unroll
    for (int ks = 0; ks < 4; ks++) {
        const float* p = wp + (size_t)(o0 + m16) * Cdim + ks * 32 + quad * 8;
        float4 f0 = *(const float4*)p;
        float4 f1 = *(const float4*)(p + 4);
        u32x4 u = {pack_bf16(f0.x, f0.y), pack_bf16(f0.z, f0.w),
                   pack_bf16(f1.x, f1.y), pack_bf16(f1.z, f1.w)};
        af[ks] = __builtin_bit_cast(bf16x8, u);
    }
    float bs[4];
    #pragma unroll
    for (int r = 0; r < 4; r++) bs[r] = bias[o0 + quad * 4 + r];
    int oq = o0 + quad * 4;

    __syncthreads();

    #pragma unroll
    for (int lt2 = 0; lt2 < 2; lt2++) {
        int n = n0 + lt2 * 16 + m16;
        bf16x8 bx[4];
        #pragma unroll
        for (int ks = 0; ks < 4; ks++)
            bx[ks] = *(const bf16x8*)(&T[lt2 * 16 + m16][ks * 32 + quad * 8]);
        f32x4 acc = {0.f, 0.f, 0.f, 0.f};
        #pragma unroll
        for (int ks = 0; ks < 4; ks++) acc = MFMA16(af[ks], bx[ks], acc);
        int b = n >> 11, l = n & (Lseq - 1);
        #pragma unroll
        for (int r = 0; r < 4; r++) {
            size_t xi = ((size_t)b * Cdim + oq + r) * Lseq + l;
            out[xi] = acc[r] + bs[r] + x[xi];
        }
    }
}

extern "C" void kernel_launch(void* const* d_in, const int* in_sizes, int n_in,
                              void* d_out, int out_size, void* d_ws, size_t ws_size,
                              hipStream_t stream) {
    const float* x      = (const float*)d_in[0];
    const float* w_qkv  = (const float*)d_in[1];
    const float* b_qkv  = (const float*)d_in[2];
    const float* w_proj = (const float*)d_in[3];
    const float* b_proj = (const float*)d_in[4];
    float* out = (float*)d_out;

    // ws: qh 4MB | kh 4MB | vh 4MB | po 8MB bf16 [2][BH][L][HD] | pl 512KB fp32
    const size_t E = (size_t)BH * Lseq * HD;   // 2M elems
    unsigned short* qh = (unsigned short*)d_ws;
    unsigned short* kh = qh + E;
    unsigned short* vh = kh + E;
    unsigned short* po = vh + E;               // [2][BH][Lseq][HD] bf16
    float* pl = (float*)(po + 2 * E);          // [2][BH][Lseq] fp32

    qkv_kernel<<<dim3(1536), dim3(256), 0, stream>>>(x, w_qkv, b_qkv, qh, kh, vh);
    attn_kernel<<<dim3(2048), dim3(256), 0, stream>>>(qh, kh, vh, po, pl);
    proj_kernel<<<dim3(1024), dim3(256), 0, stream>>>(w_proj, po, pl, b_proj, x, out);
}

// Round 15
// 117.823 us; speedup vs baseline: 1.0809x; 1.0809x over previous
//
#include <hip/hip_runtime.h>

// Problem constants: B=8, C=128, L=2048, H=4, D=32
#define Bsz 8
#define Cdim 128
#define Lseq 2048
#define NH 4
#define HD 32
#define BH 32
// 1/sqrt(D) * log2(e): scores feed v_exp_f32 (2^x) directly
#define QSCALE (0.17677669529663687f * 1.4426950408889634f)

typedef __bf16 bf16x8 __attribute__((ext_vector_type(8)));
typedef float f32x4 __attribute__((ext_vector_type(4)));
typedef unsigned u32x4 __attribute__((ext_vector_type(4)));

__device__ __forceinline__ float fexp2(float x) {
#if __has_builtin(__builtin_amdgcn_exp2f)
    return __builtin_amdgcn_exp2f(x);
#else
    return __expf(x * 0.6931471805599453f);
#endif
}

__device__ __forceinline__ unsigned short f2bf(float f) {   // RNE
    unsigned u = __builtin_bit_cast(unsigned, f);
    u += 0x7FFFu + ((u >> 16) & 1u);
    return (unsigned short)(u >> 16);
}

__device__ __forceinline__ unsigned pack_bf16(float a, float b) {  // RNE pair
    return (unsigned)f2bf(a) | ((unsigned)f2bf(b) << 16);
}

// RTZ pack of two f32 -> packed bf16x2, single v_perm_b32.
__device__ __forceinline__ unsigned pack_bf16_rtz(float a, float b) {
    return __builtin_amdgcn_perm(__builtin_bit_cast(unsigned, b),
                                 __builtin_bit_cast(unsigned, a), 0x07060302u);
}

__device__ __forceinline__ float bf_lo(unsigned u) {
    return __builtin_bit_cast(float, u << 16);
}
__device__ __forceinline__ float bf_hi(unsigned u) {
    return __builtin_bit_cast(float, u & 0xFFFF0000u);
}

#define MFMA16(A, B, C) __builtin_amdgcn_mfma_f32_16x16x32_bf16((A), (B), (C), 0, 0, 0)

// ---------------------------------------------------------------------------
// Kernel 1: QKV projection — og-merged. Grid 768 = (b, lt, og3): block =
// 128 o x 64 l; x-tile staged ONCE per 3 og (was 6 -> 24MB L2 reads, was 48).
// og3 maps block-uniformly to Q / K / V (branch-free epilogue). Wave = two
// 16-o subtiles x 64 l; B-frags loaded once per ns, reused across subtiles.
// Q,K -> [bh][l][32]; V -> kappa-permuted tile [bh][kc64][d32][pos64].
// ---------------------------------------------------------------------------
__global__ __launch_bounds__(256) void qkv_kernel(const float* __restrict__ x,
        const float* __restrict__ w, const float* __restrict__ bias,
        unsigned short* __restrict__ qh, unsigned short* __restrict__ kh,
        unsigned short* __restrict__ vh) {
    __shared__ __attribute__((aligned(16))) unsigned short T[64][132];
    int bid = blockIdx.x;
    int og3 = bid % 3;                // 0=Q, 1=K, 2=V (128 o each)
    int lt  = (bid / 3) & 31;         // 32 l-tiles of 64
    int b   = bid / 96;
    int l0 = lt * 64;
    int t = threadIdx.x;
    int lane = t & 63, wv = t >> 6;
    int m16 = lane & 15, quad = lane >> 4;

    // A-frags for 2 o-subtiles (wv*16 and 64+wv*16 within this og3 group)
    bf16x8 af[2][4];
    float bs[2][4];
    #pragma unroll
    for (int os = 0; os < 2; os++) {
        int orow = og3 * 128 + os * 64 + wv * 16;
        #pragma unroll
        for (int ks = 0; ks < 4; ks++) {
            const float* p = w + (size_t)(orow + m16) * Cdim + ks * 32 + quad * 8;
            float4 f0 = *(const float4*)p;
            float4 f1 = *(const float4*)(p + 4);
            u32x4 u = {pack_bf16(f0.x, f0.y), pack_bf16(f0.z, f0.w),
                       pack_bf16(f1.x, f1.y), pack_bf16(f1.z, f1.w)};
            af[os][ks] = __builtin_bit_cast(bf16x8, u);
        }
        #pragma unroll
        for (int r = 0; r < 4; r++) bs[os][r] = bias[orow + quad * 4 + r];
    }

    // stage x tile: T[l][c] = bf16(x[b][c][l0+l]); coalesced over l
    {
        int ll = t & 63, cg = t >> 6;
        const float* xb = x + (size_t)b * Cdim * Lseq + l0 + ll;
        #pragma unroll
        for (int i = 0; i < 16; i++) {
            int c = cg * 32 + 2 * i;
            float f0 = xb[(size_t)c * Lseq];
            float f1 = xb[(size_t)(c + 1) * Lseq];
            *(unsigned*)&T[ll][c] = pack_bf16(f0, f1);
        }
    }
    __syncthreads();

    #pragma unroll
    for (int ns = 0; ns < 4; ns++) {
        bf16x8 bx[4];   // B[k=c][n=l(m16)] — shared by both o-subtiles
        #pragma unroll
        for (int ks = 0; ks < 4; ks++)
            bx[ks] = *(const bf16x8*)(&T[ns * 16 + m16][ks * 32 + quad * 8]);
        int l = l0 + ns * 16 + m16;
        #pragma unroll
        for (int os = 0; os < 2; os++) {
            f32x4 acc = {0.f, 0.f, 0.f, 0.f};
            #pragma unroll
            for (int ks = 0; ks < 4; ks++) acc = MFMA16(af[os][ks], bx[ks], acc);
            int oq = os * 64 + wv * 16 + quad * 4;   // o within the 128-group
            if (og3 == 0) {          // Q (scaled)
                int h = oq >> 5, d0 = oq & 31;
                uint2 u;
                u.x = pack_bf16((acc[0] + bs[os][0]) * QSCALE, (acc[1] + bs[os][1]) * QSCALE);
                u.y = pack_bf16((acc[2] + bs[os][2]) * QSCALE, (acc[3] + bs[os][3]) * QSCALE);
                *(uint2*)(qh + ((size_t)(b * NH + h) * Lseq + l) * HD + d0) = u;
            } else if (og3 == 1) {   // K
                int h = oq >> 5, d0 = oq & 31;
                uint2 u;
                u.x = pack_bf16(acc[0] + bs[os][0], acc[1] + bs[os][1]);
                u.y = pack_bf16(acc[2] + bs[os][2], acc[3] + bs[os][3]);
                *(uint2*)(kh + ((size_t)(b * NH + h) * Lseq + l) * HD + d0) = u;
            } else {                 // V kappa-permuted tiled store
                int kc = l >> 6, kk = l & 63;
                int half = kk >> 5, k32 = kk & 31;
                int q_, j_;
                if (k32 < 16) { q_ = k32 >> 2; j_ = k32 & 3; }
                else          { q_ = (k32 - 16) >> 2; j_ = 4 + ((k32 - 16) & 3); }
                int pos = half * 32 + q_ * 8 + j_;
                #pragma unroll
                for (int r = 0; r < 4; r++) {
                    int o = oq + r, h = o >> 5, d = o & 31;
                    vh[(((size_t)(b * NH + h) * 32 + kc) * HD + d) * 64 + pos] =
                        f2bf(acc[r] + bs[os][r]);
                }
            }
        }
    }
}

// ---------------------------------------------------------------------------
// Kernel 2: MFMA flash attention — exact R12 structure (best: 118.3 us).
// v_exp on the trans pipe (R14 proved poly on VALU is worse: issue-cost
// parity + serial chain). Grid 2048 = (xcd bh, qt, key-half); wave = 64 q x
// 256 keys; A/B double-buffered loads; kappa-packed P (registers ARE the
// B-frag); kappa-stored V; ones-MFMA rowsums; bf16 partials to ws.
// ---------------------------------------------------------------------------
__global__ __launch_bounds__(256) void attn_kernel(
        const unsigned short* __restrict__ qh, const unsigned short* __restrict__ kh,
        const unsigned short* __restrict__ vh, unsigned short* __restrict__ po,
        float* __restrict__ pl) {
    // red_o: [4][64] rows x 18 uints = 18432 B; red_l: [4][64] float @18432
    __shared__ __attribute__((aligned(16))) char smem[19456];

    int bid = blockIdx.x;
    int xcd  = bid & 7;                 // same bh -> same XCD (K/V L2 residency)
    int rest = bid >> 3;
    int qt = rest & 31;
    int hb = rest >> 5;                 // 0..7
    int bh = xcd + 8 * (hb & 3);
    int half = hb >> 2;

    int lane = threadIdx.x & 63;
    int wv   = threadIdx.x >> 6;
    int m16  = lane & 15;
    int quad = lane >> 4;
    int l0 = qt * 64;

    bf16x8 qf[4];
    #pragma unroll
    for (int qs = 0; qs < 4; qs++)
        qf[qs] = *(const bf16x8*)(qh + ((size_t)bh * Lseq + l0 + qs * 16 + m16) * HD + quad * 8);

    bf16x8 ones;
    #pragma unroll
    for (int i = 0; i < 8; i++) ones[i] = (__bf16)1.0f;

    f32x4 oacc[4][2];
    f32x4 lacc[4];
    #pragma unroll
    for (int qs = 0; qs < 4; qs++) {
        oacc[qs][0] = f32x4{0.f, 0.f, 0.f, 0.f};
        oacc[qs][1] = f32x4{0.f, 0.f, 0.f, 0.f};
        lacc[qs]    = f32x4{0.f, 0.f, 0.f, 0.f};
    }
    f32x4 zero = {0.f, 0.f, 0.f, 0.f};

    const unsigned short* kb = kh + (size_t)bh * Lseq * HD + m16 * HD + quad * 8;
    const unsigned short* vb = vh + (size_t)bh * 32 * HD * 64;
    int kbase = half * 1024 + wv * 256;

    auto load_kv = [&](int chunk, bf16x8* kf, bf16x8* vf) {
        int k0 = kbase + chunk * 64;
        #pragma unroll
        for (int t = 0; t < 4; t++)
            kf[t] = *(const bf16x8*)(kb + (size_t)(k0 + 16 * t) * HD);
        const unsigned short* vch = vb + (size_t)(k0 >> 6) * (HD * 64);
        vf[0] = *(const bf16x8*)(vch + m16 * 64 + quad * 8);
        vf[1] = *(const bf16x8*)(vch + (16 + m16) * 64 + quad * 8);
        vf[2] = *(const bf16x8*)(vch + m16 * 64 + 32 + quad * 8);
        vf[3] = *(const bf16x8*)(vch + (16 + m16) * 64 + 32 + quad * 8);
    };

    auto compute = [&](const bf16x8* kf, const bf16x8* vf) {
        #pragma unroll
        for (int qs = 0; qs < 4; qs++) {
            f32x4 s0 = MFMA16(kf[0], qf[qs], zero);
            f32x4 s1 = MFMA16(kf[1], qf[qs], zero);
            f32x4 s2 = MFMA16(kf[2], qf[qs], zero);
            f32x4 s3 = MFMA16(kf[3], qf[qs], zero);
            float p00 = fexp2(s0[0]), p01 = fexp2(s0[1]), p02 = fexp2(s0[2]), p03 = fexp2(s0[3]);
            float p10 = fexp2(s1[0]), p11 = fexp2(s1[1]), p12 = fexp2(s1[2]), p13 = fexp2(s1[3]);
            float p20 = fexp2(s2[0]), p21 = fexp2(s2[1]), p22 = fexp2(s2[2]), p23 = fexp2(s2[3]);
            float p30 = fexp2(s3[0]), p31 = fexp2(s3[1]), p32 = fexp2(s3[2]), p33 = fexp2(s3[3]);
            // packed regs ARE the P B-frag in kappa key-order
            u32x4 lo = {pack_bf16_rtz(p00, p01), pack_bf16_rtz(p02, p03),
                        pack_bf16_rtz(p10, p11), pack_bf16_rtz(p12, p13)};
            u32x4 hi = {pack_bf16_rtz(p20, p21), pack_bf16_rtz(p22, p23),
                        pack_bf16_rtz(p30, p31), pack_bf16_rtz(p32, p33)};
            bf16x8 pfL = __builtin_bit_cast(bf16x8, lo);
            bf16x8 pfH = __builtin_bit_cast(bf16x8, hi);
            oacc[qs][0] = MFMA16(vf[0], pfL, oacc[qs][0]);
            oacc[qs][1] = MFMA16(vf[1], pfL, oacc[qs][1]);
            lacc[qs]    = MFMA16(ones,  pfL, lacc[qs]);
            oacc[qs][0] = MFMA16(vf[2], pfH, oacc[qs][0]);
            oacc[qs][1] = MFMA16(vf[3], pfH, oacc[qs][1]);
            lacc[qs]    = MFMA16(ones,  pfH, lacc[qs]);
        }
    };

    bf16x8 kA[4], vA[4], kB[4], vB[4];
    load_kv(0, kA, vA);
    load_kv(1, kB, vB);
    compute(kA, vA);
    load_kv(2, kA, vA);
    compute(kB, vB);
    load_kv(3, kB, vB);
    compute(kA, vA);
    compute(kB, vB);

    // cross-wave reduction: packed-bf16 partials, one barrier
    unsigned* red_o = (unsigned*)smem;               // [4*64 rows][18]
    float* red_l = (float*)(smem + 18432);
    #pragma unroll
    for (int qs = 0; qs < 4; qs++) {
        int row = qs * 16 + m16;
        unsigned* rw = red_o + (size_t)(wv * 64 + row) * 18;
        *(uint2*)(rw + 2 * quad) =
            make_uint2(pack_bf16_rtz(oacc[qs][0][0], oacc[qs][0][1]),
                       pack_bf16_rtz(oacc[qs][0][2], oacc[qs][0][3]));
        *(uint2*)(rw + 8 + 2 * quad) =
            make_uint2(pack_bf16_rtz(oacc[qs][1][0], oacc[qs][1][1]),
                       pack_bf16_rtz(oacc[qs][1][2], oacc[qs][1][3]));
        if (quad == 0) red_l[wv * 64 + row] = lacc[qs][0];  // rowsum (replicated)
    }
    __syncthreads();

    // combine 4 waves -> UNNORMALIZED bf16 partials to ws
    int q = threadIdx.x >> 2;
    int s4 = (threadIdx.x & 3) * 4;
    float a8[8] = {0.f, 0.f, 0.f, 0.f, 0.f, 0.f, 0.f, 0.f};
    float lt = 0.f;
    #pragma unroll
    for (int w = 0; w < 4; w++) {
        const unsigned* rr = red_o + (size_t)(w * 64 + q) * 18 + s4;
        uint2 ua = *(const uint2*)(rr);
        uint2 ub = *(const uint2*)(rr + 2);
        a8[0] += bf_lo(ua.x); a8[1] += bf_hi(ua.x);
        a8[2] += bf_lo(ua.y); a8[3] += bf_hi(ua.y);
        a8[4] += bf_lo(ub.x); a8[5] += bf_hi(ub.x);
        a8[6] += bf_lo(ub.y); a8[7] += bf_hi(ub.y);
        lt += red_l[w * 64 + q];
    }
    int d0 = (threadIdx.x & 3) * 8;
    uint4 u;
    u.x = pack_bf16(a8[0], a8[1]);
    u.y = pack_bf16(a8[2], a8[3]);
    u.z = pack_bf16(a8[4], a8[5]);
    u.w = pack_bf16(a8[6], a8[7]);
    *(uint4*)(po + ((size_t)(half * BH + bh) * Lseq + l0 + q) * HD + d0) = u;
    if ((threadIdx.x & 3) == 0)
        pl[(size_t)(half * BH + bh) * Lseq + l0 + q] = lt;
}

// ---------------------------------------------------------------------------
// Kernel 3: combine key-halves + normalize + projection + bias + residual.
// (unchanged from R12) Grid 1024: block = 64 o x 32 n.
// ---------------------------------------------------------------------------
__global__ __launch_bounds__(256) void proj_kernel(const float* __restrict__ wp,
        const unsigned short* __restrict__ po, const float* __restrict__ pl,
        const float* __restrict__ bias, const float* __restrict__ x,
        float* __restrict__ out) {
    __shared__ __attribute__((aligned(16))) unsigned short T[32][132];
    int bid = blockIdx.x;
    int ot = bid & 1;
    int nt = bid >> 1;                // 0..511, 32-n tiles
    int n0 = nt * 32;
    int t = threadIdx.x;

    {
        int nl = t >> 3, g = t & 7;
        int h = g >> 1, d0 = (g & 1) * 16;
        int n = n0 + nl, b = n >> 11, l = n & (Lseq - 1);
        int bh = b * NH + h;
        const unsigned short* p0 = po + ((size_t)bh * Lseq + l) * HD + d0;
        const unsigned short* p1 = po + ((size_t)(BH + bh) * Lseq + l) * HD + d0;
        float inv = 1.0f / (pl[(size_t)bh * Lseq + l] + pl[(size_t)(BH + bh) * Lseq + l]);
        uint4 a0 = *(const uint4*)p0, a1 = *(const uint4*)(p0 + 8);
        uint4 b0 = *(const uint4*)p1, b1 = *(const uint4*)(p1 + 8);
        uint4 u0, u1;
        u0.x = pack_bf16((bf_lo(a0.x) + bf_lo(b0.x)) * inv, (bf_hi(a0.x) + bf_hi(b0.x)) * inv);
        u0.y = pack_bf16((bf_lo(a0.y) + bf_lo(b0.y)) * inv, (bf_hi(a0.y) + bf_hi(b0.y)) * inv);
        u0.z = pack_bf16((bf_lo(a0.z) + bf_lo(b0.z)) * inv, (bf_hi(a0.z) + bf_hi(b0.z)) * inv);
        u0.w = pack_bf16((bf_lo(a0.w) + bf_lo(b0.w)) * inv, (bf_hi(a0.w) + bf_hi(b0.w)) * inv);
        u1.x = pack_bf16((bf_lo(a1.x) + bf_lo(b1.x)) * inv, (bf_hi(a1.x) + bf_hi(b1.x)) * inv);
        u1.y = pack_bf16((bf_lo(a1.y) + bf_lo(b1.y)) * inv, (bf_hi(a1.y) + bf_hi(b1.y)) * inv);
        u1.z = pack_bf16((bf_lo(a1.z) + bf_lo(b1.z)) * inv, (bf_hi(a1.z) + bf_hi(b1.z)) * inv);
        u1.w = pack_bf16((bf_lo(a1.w) + bf_lo(b1.w)) * inv, (bf_hi(a1.w) + bf_hi(b1.w)) * inv);
        int c0 = g * 16;
        *(uint4*)&T[nl][c0]     = u0;
        *(uint4*)&T[nl][c0 + 8] = u1;
    }

    int lane = t & 63;
    int wv = t >> 6;
    int m16 = lane & 15, quad = lane >> 4;
    int o0 = ot * 64 + wv * 16;

    bf16x8 af[4];
    #pragma unroll
    for (int ks = 0; ks < 4; ks++) {
        const float* p = wp + (size_t)(o0 + m16) * Cdim + ks * 32 + quad * 8;
        float4 f0 = *(const float4*)p;
        float4 f1 = *(const float4*)(p + 4);
        u32x4 u = {pack_bf16(f0.x, f0.y), pack_bf16(f0.z, f0.w),
                   pack_bf16(f1.x, f1.y), pack_bf16(f1.z, f1.w)};
        af[ks] = __builtin_bit_cast(bf16x8, u);
    }
    float bs[4];
    #pragma unroll
    for (int r = 0; r < 4; r++) bs[r] = bias[o0 + quad * 4 + r];
    int oq = o0 + quad * 4;

    __syncthreads();

    #pragma unroll
    for (int lt2 = 0; lt2 < 2; lt2++) {
        int n = n0 + lt2 * 16 + m16;
        bf16x8 bx[4];
        #pragma unroll
        for (int ks = 0; ks < 4; ks++)
            bx[ks] = *(const bf16x8*)(&T[lt2 * 16 + m16][ks * 32 + quad * 8]);
        f32x4 acc = {0.f, 0.f, 0.f, 0.f};
        #pragma unroll
        for (int ks = 0; ks < 4; ks++) acc = MFMA16(af[ks], bx[ks], acc);
        int b = n >> 11, l = n & (Lseq - 1);
        #pragma unroll
        for (int r = 0; r < 4; r++) {
            size_t xi = ((size_t)b * Cdim + oq + r) * Lseq + l;
            out[xi] = acc[r] + bs[r] + x[xi];
        }
    }
}

extern "C" void kernel_launch(void* const* d_in, const int* in_sizes, int n_in,
                              void* d_out, int out_size, void* d_ws, size_t ws_size,
                              hipStream_t stream) {
    const float* x      = (const float*)d_in[0];
    const float* w_qkv  = (const float*)d_in[1];
    const float* b_qkv  = (const float*)d_in[2];
    const float* w_proj = (const float*)d_in[3];
    const float* b_proj = (const float*)d_in[4];
    float* out = (float*)d_out;

    // ws: qh 4MB | kh 4MB | vh 4MB | po 8MB bf16 [2][BH][L][HD] | pl 512KB fp32
    const size_t E = (size_t)BH * Lseq * HD;   // 2M elems
    unsigned short* qh = (unsigned short*)d_ws;
    unsigned short* kh = qh + E;
    unsigned short* vh = kh + E;
    unsigned short* po = vh + E;               // [2][BH][Lseq][HD] bf16
    float* pl = (float*)(po + 2 * E);          // [2][BH][Lseq] fp32

    qkv_kernel<<<dim3(768), dim3(256), 0, stream>>>(x, w_qkv, b_qkv, qh, kh, vh);
    attn_kernel<<<dim3(2048), dim3(256), 0, stream>>>(qh, kh, vh, po, pl);
    proj_kernel<<<dim3(1024), dim3(256), 0, stream>>>(w_proj, po, pl, b_proj, x, out);
}